// Round 1
// baseline (19616.280 us; speedup 1.0000x reference)
//
#include <hip/hip_runtime.h>
#include <hip/hip_bf16.h>
#include <stdint.h>

// GraphEncoderTriangleSoup on MI355X (gfx950).
// Decomposition:
//   edge_conv(x) = ((segsum_dst relu(C[dst]+B[src])) * rdeg) @ w2 + b2
//   where C = x@(w1_top - w1_bot) + b1, B = x@w1_bot   (node-level GEMMs)
// Activations stored bf16; accumulations fp32. Hidden dim chunked at 384.
// Workspace requirement ~580 MB.

typedef __hip_bfloat16 bf16;
#define CHUNK 384

static inline int cdiv(int a, int b) { return (a + b - 1) / b; }

__device__ __forceinline__ float bf2f(bf16 v) { return __bfloat162float(v); }
__device__ __forceinline__ bf16 f2bf(float v) { return __float2bfloat16(v); }

// ---------------- embed: x[N,16] -> h[N,196] (bf16) ----------------
__global__ __launch_bounds__(256) void k_embed(const float* __restrict__ x,
                                               bf16* __restrict__ h, int N) {
  int idx = blockIdx.x * 256 + threadIdx.x;
  if (idx >= N * 196) return;
  int n = idx / 196;
  int c = idx - n * 196;
  float v;
  if (c >= 189) {
    v = x[n * 16 + 9 + (c - 189)];
  } else {
    int g = c / 63;           // which coordinate triple
    int cc = c - g * 63;
    const float* p = x + n * 16 + g * 3;
    if (cc < 3) {
      v = p[cc];
    } else {
      int t = cc - 3;
      int comp = t / 20;          // component 0..2
      int rem = t - comp * 20;    // freq*2 + (0=sin,1=cos)
      float ang = p[comp] * (float)(1 << (rem >> 1));
      v = (rem & 1) ? cosf(ang) : sinf(ang);
    }
  }
  h[idx] = f2bf(v);
}

// ---------------- degree counting / reciprocals ----------------
__global__ __launch_bounds__(256) void k_count(const int* __restrict__ idxs,
                                               int* __restrict__ deg, int M) {
  int i = blockIdx.x * 256 + threadIdx.x;
  if (i < M) atomicAdd(&deg[idxs[i]], 1);
}

__global__ __launch_bounds__(256) void k_recip(const int* __restrict__ deg,
                                               float* __restrict__ r, int n) {
  int i = blockIdx.x * 256 + threadIdx.x;
  if (i < n) {
    int d = deg[i];
    r[i] = d > 0 ? 1.f / (float)d : 0.f;  // 0 => gates out b2 for isolated nodes
  }
}

// ---------------- Wd = w1_top - w1_bot ----------------
__global__ __launch_bounds__(256) void k_wdiff(const float* __restrict__ w1,
                                               float* __restrict__ Wd, int M) {
  int i = blockIdx.x * 256 + threadIdx.x;
  if (i < M) Wd[i] = w1[i] - w1[M + i];
}

// ---------------- GEMM1: C = A@Wd + b1, B = A@Wb  (A bf16 [N,lda], W fp32 [F,H]) ----------------
// 64x64 tile, 16x16 threads, 4x4 micro-tile, dual accumulator.
__global__ __launch_bounds__(256) void gemm1_kernel(
    const bf16* __restrict__ A, int lda,
    const float* __restrict__ Wd, const float* __restrict__ Wb,
    const float* __restrict__ b1,
    bf16* __restrict__ outC, bf16* __restrict__ outB,
    int N, int F, int H, int c0, int Hc) {
  __shared__ float sA[64][17];
  __shared__ float sWd[16][64];
  __shared__ float sWb[16][64];
  const int tid = threadIdx.x;
  const int tx = tid & 15, ty = tid >> 4;
  const int tx4 = tx * 4, ty4 = ty * 4;
  const int row0 = blockIdx.x * 64;
  const int col0 = blockIdx.y * 64;
  float accC[4][4] = {{0.f}}, accB[4][4] = {{0.f}};
  const int kTiles = (F + 15) >> 4;
  const int jW = tid & 63, kW0 = tid >> 6;
  const int cW = c0 + col0 + jW;
  for (int kt = 0; kt < kTiles; ++kt) {
    const int k0 = kt << 4;
#pragma unroll
    for (int u = 0; u < 4; ++u) {          // A tile 64x16
      int rr = ty + u * 16;
      int r = row0 + rr, k = k0 + tx;
      float v = 0.f;
      if (r < N && k < F) v = bf2f(A[(size_t)r * lda + k]);
      sA[rr][tx] = v;
    }
#pragma unroll
    for (int u = 0; u < 4; ++u) {          // W tiles 16x64
      int kk = kW0 + u * 4;
      int k = k0 + kk;
      float vd = 0.f, vb = 0.f;
      if (k < F) {
        size_t o = (size_t)k * H + cW;
        vd = Wd[o];
        vb = Wb[o];
      }
      sWd[kk][jW] = vd;
      sWb[kk][jW] = vb;
    }
    __syncthreads();
#pragma unroll
    for (int k = 0; k < 16; ++k) {
      float a[4];
#pragma unroll
      for (int i = 0; i < 4; ++i) a[i] = sA[ty4 + i][k];
      float4 wd = *(const float4*)&sWd[k][tx4];
      float4 wb = *(const float4*)&sWb[k][tx4];
      float wdv[4] = {wd.x, wd.y, wd.z, wd.w};
      float wbv[4] = {wb.x, wb.y, wb.z, wb.w};
#pragma unroll
      for (int i = 0; i < 4; ++i)
#pragma unroll
        for (int j = 0; j < 4; ++j) {
          accC[i][j] += a[i] * wdv[j];
          accB[i][j] += a[i] * wbv[j];
        }
    }
    __syncthreads();
  }
  float b1v[4];
#pragma unroll
  for (int j = 0; j < 4; ++j) b1v[j] = b1[c0 + col0 + tx4 + j];
#pragma unroll
  for (int i = 0; i < 4; ++i) {
    int r = row0 + ty4 + i;
    if (r >= N) continue;
    size_t base = (size_t)r * Hc + col0 + tx4;
#pragma unroll
    for (int j = 0; j < 4; ++j) {
      outC[base + j] = f2bf(accC[i][j] + b1v[j]);
      outB[base + j] = f2bf(accB[i][j]);
    }
  }
}

// ---------------- edge kernel: S[dst] += relu(C[dst] + B[src]) ----------------
__global__ __launch_bounds__(256) void k_edge(const int* __restrict__ ei, int E,
                                              const bf16* __restrict__ C,
                                              const bf16* __restrict__ B,
                                              float* __restrict__ S, int Hc) {
  int gw = (blockIdx.x * 256 + threadIdx.x) >> 6;  // one wave per edge
  int lane = threadIdx.x & 63;
  if (gw >= E) return;
  int src = ei[gw], dst = ei[E + gw];
  const uint32_t* Crow = reinterpret_cast<const uint32_t*>(C + (size_t)dst * Hc);
  const uint32_t* Brow = reinterpret_cast<const uint32_t*>(B + (size_t)src * Hc);
  float* Srow = S + (size_t)dst * Hc;
  for (int j2 = lane; j2 * 2 < Hc; j2 += 64) {
    uint32_t uc = Crow[j2], ub = Brow[j2];
    float v0 = __uint_as_float(uc << 16) + __uint_as_float(ub << 16);
    float v1 = __uint_as_float(uc & 0xffff0000u) + __uint_as_float(ub & 0xffff0000u);
    int j = j2 * 2;
    if (v0 > 0.f) unsafeAtomicAdd(&Srow[j], v0);       // relu==0 contributes nothing
    if (v1 > 0.f) unsafeAtomicAdd(&Srow[j + 1], v1);
  }
}

// ---------------- GEMM2: E (+)= (S@W) * rdeg[row] (+ b2 if first & deg>0) ----------------
__global__ __launch_bounds__(256) void gemm2_kernel(
    const float* __restrict__ S, const float* __restrict__ W,  // W = w2 + c0*O
    const float* __restrict__ b2, const float* __restrict__ rdeg,
    float* __restrict__ Eo, int N, int K, int O, int first) {
  __shared__ float sA[64][17];
  __shared__ float sW[16][64];
  const int tid = threadIdx.x;
  const int tx = tid & 15, ty = tid >> 4;
  const int tx4 = tx * 4, ty4 = ty * 4;
  const int row0 = blockIdx.x * 64;
  const int col0 = blockIdx.y * 64;
  float acc[4][4] = {{0.f}};
  const int kTiles = (K + 15) >> 4;
  const int jW = tid & 63, kW0 = tid >> 6;
  for (int kt = 0; kt < kTiles; ++kt) {
    const int k0 = kt << 4;
#pragma unroll
    for (int u = 0; u < 4; ++u) {
      int rr = ty + u * 16;
      int r = row0 + rr, k = k0 + tx;
      float v = 0.f;
      if (r < N && k < K) v = S[(size_t)r * K + k];
      sA[rr][tx] = v;
    }
#pragma unroll
    for (int u = 0; u < 4; ++u) {
      int kk = kW0 + u * 4;
      int k = k0 + kk;
      int c = col0 + jW;
      float v = 0.f;
      if (k < K && c < O) v = W[(size_t)k * O + c];
      sW[kk][jW] = v;
    }
    __syncthreads();
#pragma unroll
    for (int k = 0; k < 16; ++k) {
      float a[4];
#pragma unroll
      for (int i = 0; i < 4; ++i) a[i] = sA[ty4 + i][k];
      float4 w = *(const float4*)&sW[k][tx4];
      float wv[4] = {w.x, w.y, w.z, w.w};
#pragma unroll
      for (int i = 0; i < 4; ++i)
#pragma unroll
        for (int j = 0; j < 4; ++j) acc[i][j] += a[i] * wv[j];
    }
    __syncthreads();
  }
#pragma unroll
  for (int i = 0; i < 4; ++i) {
    int r = row0 + ty4 + i;
    if (r >= N) continue;
    float rd = rdeg[r];
#pragma unroll
    for (int j = 0; j < 4; ++j) {
      int c = col0 + tx4 + j;
      if (c >= O) continue;
      float v = acc[i][j] * rd;
      size_t o = (size_t)r * O + c;
      if (first) {
        if (rd != 0.f) v += b2[c];
        Eo[o] = v;
      } else {
        Eo[o] += v;
      }
    }
  }
}

// ---------------- BN stats: column sums + sumsq ----------------
__global__ __launch_bounds__(256) void k_bn_stats(const float* __restrict__ Ef,
                                                  float* __restrict__ stats, int N, int O) {
  int r0 = blockIdx.x * 256;
  int rend = min(r0 + 256, N);
  for (int c = threadIdx.x; c < O; c += 256) {
    float s = 0.f, q = 0.f;
    for (int r = r0; r < rend; ++r) {
      float v = Ef[(size_t)r * O + c];
      s += v;
      q += v * v;
    }
    unsafeAtomicAdd(&stats[c], s);
    unsafeAtomicAdd(&stats[O + c], q);
  }
}

__global__ __launch_bounds__(256) void k_bn_finalize(const float* __restrict__ stats,
                                                     const float* __restrict__ gamma,
                                                     const float* __restrict__ beta,
                                                     float* __restrict__ scale,
                                                     float* __restrict__ shift, int N, int O) {
  int c = blockIdx.x * 256 + threadIdx.x;
  if (c >= O) return;
  float mu = stats[c] / (float)N;
  float var = stats[O + c] / (float)N - mu * mu;
  float sc = gamma[c] * rsqrtf(var + 1e-5f);
  scale[c] = sc;
  shift[c] = beta[c] - mu * sc;
}

// ---------------- BN-apply + relu + face scatter (vertex sums) ----------------
__global__ __launch_bounds__(256) void k_scatter(const float* __restrict__ Ef,
                                                 const int* __restrict__ faces,
                                                 const float* __restrict__ scale,
                                                 const float* __restrict__ shift,
                                                 int use_bn, float* __restrict__ Vf,
                                                 int N, int O, int O3) {
  int idx = blockIdx.x * 256 + threadIdx.x;
  if (idx >= N * O) return;
  int n = idx / O;
  int c = idx - n * O;
  float v = Ef[idx];
  if (use_bn) v = fmaxf(fmaf(v, scale[c], shift[c]), 0.f);
  int g = c / O3;
  int vert = faces[n * 3 + g];
  unsafeAtomicAdd(&Vf[(size_t)vert * O3 + (c - g * O3)], v);
}

// ---------------- vertex mean gather back ----------------
__global__ __launch_bounds__(256) void k_gather_bf16(const float* __restrict__ Vf,
                                                     const int* __restrict__ faces,
                                                     const float* __restrict__ rv,
                                                     bf16* __restrict__ out,
                                                     int N, int O, int O3) {
  int idx = blockIdx.x * 256 + threadIdx.x;
  if (idx >= N * O) return;
  int n = idx / O;
  int c = idx - n * O;
  int g = c / O3;
  int vert = faces[n * 3 + g];
  out[idx] = f2bf(Vf[(size_t)vert * O3 + (c - g * O3)] * rv[vert]);
}

__global__ __launch_bounds__(256) void k_gather_f32(const float* __restrict__ Vf,
                                                    const int* __restrict__ faces,
                                                    const float* __restrict__ rv,
                                                    float* __restrict__ out,
                                                    int N, int O, int O3) {
  int idx = blockIdx.x * 256 + threadIdx.x;
  if (idx >= N * O) return;
  int n = idx / O;
  int c = idx - n * O;
  int g = c / O3;
  int vert = faces[n * 3 + g];
  out[idx] = Vf[(size_t)vert * O3 + (c - g * O3)] * rv[vert];
}

extern "C" void kernel_launch(void* const* d_in, const int* in_sizes, int n_in,
                              void* d_out, int out_size, void* d_ws, size_t ws_size,
                              hipStream_t stream) {
  (void)n_in; (void)out_size; (void)ws_size;
  const float* x = (const float*)d_in[0];
  const int* ei = (const int*)d_in[1];
  const int* faces = (const int*)d_in[2];
  const int N = in_sizes[0] / 16;
  const int E = in_sizes[1] / 2;
  const int V = 50000;  // num_vertices (d_in[3] is a device scalar; fixed problem size)

  // ---- workspace carve (~580 MB total) ----
  char* p = (char*)d_ws;
  auto carve = [&](size_t bytes) -> char* {
    char* r = p;
    p += (bytes + 255) & ~(size_t)255;
    return r;
  };
  bf16* buf_h = (bf16*)carve((size_t)N * 384 * sizeof(bf16));    // node features (lda = F per layer)
  float* buf_e = (float*)carve((size_t)N * 384 * sizeof(float)); // edge_conv output (layers 1-4)
  bf16* buf_C = (bf16*)carve((size_t)N * CHUNK * sizeof(bf16));
  bf16* buf_B = (bf16*)carve((size_t)N * CHUNK * sizeof(bf16));
  float* buf_S = (float*)carve((size_t)N * CHUNK * sizeof(float));
  float* buf_V = (float*)carve((size_t)V * 192 * sizeof(float));
  float* buf_Wd = (float*)carve((size_t)384 * 1152 * sizeof(float));
  int* ideg = (int*)carve((size_t)N * 4);
  int* ivdeg = (int*)carve((size_t)V * 4);
  float* rdegN = (float*)carve((size_t)N * 4);
  float* rdegV = (float*)carve((size_t)V * 4);
  float* stats = (float*)carve(2 * 576 * 4);
  float* scale = (float*)carve(576 * 4);
  float* shift = (float*)carve(576 * 4);

  // ---- degrees (in-degree over dst; vertex counts over faces) ----
  hipMemsetAsync(ideg, 0, (size_t)N * 4, stream);
  hipMemsetAsync(ivdeg, 0, (size_t)V * 4, stream);
  k_count<<<cdiv(E, 256), 256, 0, stream>>>(ei + E, ideg, E);
  k_count<<<cdiv(3 * N, 256), 256, 0, stream>>>(faces, ivdeg, 3 * N);
  k_recip<<<cdiv(N, 256), 256, 0, stream>>>(ideg, rdegN, N);
  k_recip<<<cdiv(V, 256), 256, 0, stream>>>(ivdeg, rdegV, V);

  // ---- NeRF embedding ----
  k_embed<<<cdiv(N * 196, 256), 256, 0, stream>>>(x, buf_h, N);

  const int LF[5] = {196, 96, 192, 384, 384};
  const int LH[5] = {192, 384, 768, 768, 1152};
  const int LO[5] = {96, 192, 384, 384, 576};

  for (int l = 0; l < 5; ++l) {
    const int F = LF[l], H = LH[l], O = LO[l], O3 = O / 3;
    const float* w1 = (const float*)d_in[4 + l * 4];
    const float* b1 = (const float*)d_in[5 + l * 4];
    const float* w2 = (const float*)d_in[6 + l * 4];
    const float* b2 = (const float*)d_in[7 + l * 4];
    float* Ebuf = (l == 4) ? (float*)d_out : buf_e;

    k_wdiff<<<cdiv(F * H, 256), 256, 0, stream>>>(w1, buf_Wd, F * H);

    for (int c0 = 0; c0 < H; c0 += CHUNK) {
      int Hc = (H - c0 < CHUNK) ? (H - c0) : CHUNK;
      dim3 g1(cdiv(N, 64), Hc / 64);
      gemm1_kernel<<<g1, 256, 0, stream>>>(buf_h, F, buf_Wd, w1 + (size_t)F * H, b1,
                                           buf_C, buf_B, N, F, H, c0, Hc);
      hipMemsetAsync(buf_S, 0, (size_t)N * Hc * 4, stream);
      k_edge<<<cdiv(E * 64, 256), 256, 0, stream>>>(ei, E, buf_C, buf_B, buf_S, Hc);
      dim3 g2(cdiv(N, 64), cdiv(O, 64));
      gemm2_kernel<<<g2, 256, 0, stream>>>(buf_S, w2 + (size_t)c0 * O, b2, rdegN, Ebuf,
                                           N, Hc, O, c0 == 0 ? 1 : 0);
    }

    if (l < 4) {
      hipMemsetAsync(stats, 0, (size_t)2 * O * 4, stream);
      k_bn_stats<<<cdiv(N, 256), 256, 0, stream>>>(Ebuf, stats, N, O);
      k_bn_finalize<<<cdiv(O, 256), 256, 0, stream>>>(
          stats, (const float*)d_in[24 + l * 2], (const float*)d_in[25 + l * 2],
          scale, shift, N, O);
    }

    hipMemsetAsync(buf_V, 0, (size_t)V * O3 * 4, stream);
    k_scatter<<<cdiv(N * O, 256), 256, 0, stream>>>(Ebuf, faces, scale, shift,
                                                    (l < 4) ? 1 : 0, buf_V, N, O, O3);
    if (l < 4)
      k_gather_bf16<<<cdiv(N * O, 256), 256, 0, stream>>>(buf_V, faces, rdegV, buf_h, N, O, O3);
    else
      k_gather_f32<<<cdiv(N * O, 256), 256, 0, stream>>>(buf_V, faces, rdegV, (float*)d_out, N, O, O3);
  }
}

// Round 2
// 12821.707 us; speedup vs baseline: 1.5299x; 1.5299x over previous
//
#include <hip/hip_runtime.h>
#include <hip/hip_bf16.h>
#include <stdint.h>

// GraphEncoderTriangleSoup on MI355X (gfx950).  Round 2: bf16 MFMA GEMMs.
// Decomposition:
//   edge_conv(x) = ((segsum_dst relu(C[dst]+B[src])) * rdeg) @ w2 + b2
//   C = x@(w1_top - w1_bot) + b1, B = x@w1_bot   (node-level GEMMs, MFMA bf16)
// Weights transposed+bf16-cast once per layer, K-padded to x32 (no K guards).

typedef __hip_bfloat16 bf16;
typedef __attribute__((ext_vector_type(8))) short bf16x8;
typedef __attribute__((ext_vector_type(4))) float f32x4;
#define CHUNK 384

static inline int cdiv(int a, int b) { return (a + b - 1) / b; }

__device__ __forceinline__ float bf2f(bf16 v) { return __bfloat162float(v); }
__device__ __forceinline__ bf16 f2bf(float v) { return __float2bfloat16(v); }
__device__ __forceinline__ unsigned short f2bs(float v) {
  bf16 h = __float2bfloat16(v);
  return *reinterpret_cast<unsigned short*>(&h);
}

// ---------------- embed: x[N,16] -> h[N,224] (bf16, cols 196..223 zero) ----------------
__global__ __launch_bounds__(256) void k_embed(const float* __restrict__ x,
                                               bf16* __restrict__ h, int N) {
  int idx = blockIdx.x * 256 + threadIdx.x;
  if (idx >= N * 224) return;
  int n = idx / 224;
  int c = idx - n * 224;
  float v = 0.f;
  if (c >= 196) {
    v = 0.f;
  } else if (c >= 189) {
    v = x[n * 16 + 9 + (c - 189)];
  } else {
    int g = c / 63;
    int cc = c - g * 63;
    const float* p = x + n * 16 + g * 3;
    if (cc < 3) {
      v = p[cc];
    } else {
      int t = cc - 3;
      int comp = t / 20;
      int rem = t - comp * 20;
      float ang = p[comp] * (float)(1 << (rem >> 1));
      v = (rem & 1) ? cosf(ang) : sinf(ang);
    }
  }
  h[idx] = f2bf(v);
}

// ---------------- degree counting / reciprocals ----------------
__global__ __launch_bounds__(256) void k_count(const int* __restrict__ idxs,
                                               int* __restrict__ deg, int M) {
  int i = blockIdx.x * 256 + threadIdx.x;
  if (i < M) atomicAdd(&deg[idxs[i]], 1);
}

__global__ __launch_bounds__(256) void k_recip(const int* __restrict__ deg,
                                               float* __restrict__ r, int n) {
  int i = blockIdx.x * 256 + threadIdx.x;
  if (i < n) {
    int d = deg[i];
    r[i] = d > 0 ? 1.f / (float)d : 0.f;
  }
}

// ---------------- weight prep: WdT/WbT [H][F_pad] bf16 from w1 [2F][H] fp32 ----------------
__global__ __launch_bounds__(256) void k_prep_w1(const float* __restrict__ w1,
                                                 bf16* __restrict__ WdT,
                                                 bf16* __restrict__ WbT,
                                                 int F, int H, int F_pad) {
  int idx = blockIdx.x * 256 + threadIdx.x;
  if (idx >= H * F_pad) return;
  int n = idx / F_pad;
  int k = idx - n * F_pad;
  float vd = 0.f, vb = 0.f;
  if (k < F) {
    float top = w1[(size_t)k * H + n];
    float bot = w1[(size_t)(F + k) * H + n];
    vd = top - bot;
    vb = bot;
  }
  WdT[idx] = f2bf(vd);
  WbT[idx] = f2bf(vb);
}

// ---------------- weight prep: W2T [O][H] bf16 from w2 [H][O] fp32 ----------------
__global__ __launch_bounds__(256) void k_prep_w2(const float* __restrict__ w2,
                                                 bf16* __restrict__ W2T, int H, int O) {
  int idx = blockIdx.x * 256 + threadIdx.x;
  if (idx >= O * H) return;
  int n = idx / H;
  int k = idx - n * H;
  W2T[idx] = f2bf(w2[(size_t)k * O + n]);
}

// ---------------- GEMM1 (MFMA): C = A@Wd + b1, B = A@Wb ----------------
// A bf16 [N][lda=K_pad]; WdT/WbT bf16 [Hc][K_pad] (chunk rows); out bf16 [N][Hc].
// 128x128 tile, 4 waves 2x2, wave = 64x64 (4x4 frags of 16x16x32), dual acc.
__global__ __launch_bounds__(256) void gemm1_mfma(
    const bf16* __restrict__ A, int lda,
    const bf16* __restrict__ WdT, const bf16* __restrict__ WbT,
    const float* __restrict__ b1, int c0,
    bf16* __restrict__ outC, bf16* __restrict__ outB,
    int N, int K_pad, int Hc) {
  __shared__ bf16 sA[128][40];
  __shared__ bf16 sBd[128][40];
  __shared__ bf16 sBb[128][40];
  const int tid = threadIdx.x;
  const int lane = tid & 63, wave = tid >> 6;
  const int wm = wave & 1, wn = wave >> 1;
  const int lr = lane & 15, quad = lane >> 4;
  const int m_blk = blockIdx.x * 128;
  const int n_blk = blockIdx.y * 128;
  const int sr = tid & 127;
  const int sc0 = (tid >> 7) * 8;
  f32x4 accC[4][4], accB[4][4];
#pragma unroll
  for (int i = 0; i < 4; ++i)
#pragma unroll
    for (int j = 0; j < 4; ++j) {
      accC[i][j] = (f32x4){0.f, 0.f, 0.f, 0.f};
      accB[i][j] = (f32x4){0.f, 0.f, 0.f, 0.f};
    }
  const int kTiles = K_pad >> 5;
  for (int kt = 0; kt < kTiles; ++kt) {
    const int k0 = kt << 5;
#pragma unroll
    for (int u = 0; u < 2; ++u) {
      int c = sc0 + u * 16;
      int r = m_blk + sr;
      uint4 va = {0, 0, 0, 0};
      if (r < N) va = *(const uint4*)(A + (size_t)r * lda + k0 + c);
      *(uint4*)&sA[sr][c] = va;
      int nr = n_blk + sr;
      uint4 vd = {0, 0, 0, 0}, vb = {0, 0, 0, 0};
      if (nr < Hc) {
        size_t o = (size_t)nr * K_pad + k0 + c;
        vd = *(const uint4*)(WdT + o);
        vb = *(const uint4*)(WbT + o);
      }
      *(uint4*)&sBd[sr][c] = vd;
      *(uint4*)&sBb[sr][c] = vb;
    }
    __syncthreads();
    bf16x8 af[4];
#pragma unroll
    for (int im = 0; im < 4; ++im)
      af[im] = *(const bf16x8*)&sA[wm * 64 + im * 16 + lr][quad * 8];
#pragma unroll
    for (int jn = 0; jn < 4; ++jn) {
      bf16x8 bd = *(const bf16x8*)&sBd[wn * 64 + jn * 16 + lr][quad * 8];
      bf16x8 bb = *(const bf16x8*)&sBb[wn * 64 + jn * 16 + lr][quad * 8];
#pragma unroll
      for (int im = 0; im < 4; ++im) {
        accC[im][jn] = __builtin_amdgcn_mfma_f32_16x16x32_bf16(af[im], bd, accC[im][jn], 0, 0, 0);
        accB[im][jn] = __builtin_amdgcn_mfma_f32_16x16x32_bf16(af[im], bb, accB[im][jn], 0, 0, 0);
      }
    }
    __syncthreads();
  }
#pragma unroll
  for (int jn = 0; jn < 4; ++jn) {
    int c = n_blk + wn * 64 + jn * 16 + lr;
    if (c >= Hc) continue;
    float bv = b1[c0 + c];
#pragma unroll
    for (int im = 0; im < 4; ++im) {
      int mb = m_blk + wm * 64 + im * 16 + quad * 4;
#pragma unroll
      for (int rg = 0; rg < 4; ++rg) {
        int r = mb + rg;
        if (r >= N) continue;
        size_t o = (size_t)r * Hc + c;
        outC[o] = f2bf(accC[im][jn][rg] + bv);
        outB[o] = f2bf(accB[im][jn][rg]);
      }
    }
  }
}

// ---------------- GEMM2 (MFMA): Eo (+)= (S@W2) * rdeg (+b2 if first&&deg>0) ----------------
// S fp32 [N][lda=Kc] (bf16-cast during staging); W2T bf16 rows [O], stride ldw, col-offset pre-applied.
__global__ __launch_bounds__(256) void gemm2_mfma(
    const float* __restrict__ S, int lda,
    const bf16* __restrict__ W2T, int ldw,
    const float* __restrict__ b2, const float* __restrict__ rdeg,
    float* __restrict__ Eo, int N, int Kc, int O, int first) {
  __shared__ bf16 sA[128][40];
  __shared__ bf16 sB[128][40];
  const int tid = threadIdx.x;
  const int lane = tid & 63, wave = tid >> 6;
  const int wm = wave & 1, wn = wave >> 1;
  const int lr = lane & 15, quad = lane >> 4;
  const int m_blk = blockIdx.x * 128;
  const int n_blk = blockIdx.y * 128;
  const int sr = tid & 127;
  const int sc0f = (tid >> 7) * 4;   // fp32 staging: chunks of 4 floats
  const int sc0b = (tid >> 7) * 8;   // bf16 staging: chunks of 8
  f32x4 acc[4][4];
#pragma unroll
  for (int i = 0; i < 4; ++i)
#pragma unroll
    for (int j = 0; j < 4; ++j) acc[i][j] = (f32x4){0.f, 0.f, 0.f, 0.f};
  const int kTiles = Kc >> 5;
  for (int kt = 0; kt < kTiles; ++kt) {
    const int k0 = kt << 5;
#pragma unroll
    for (int u = 0; u < 4; ++u) {   // A: 128x32 fp32 -> bf16
      int c = sc0f + u * 8;
      int r = m_blk + sr;
      float4 v = {0.f, 0.f, 0.f, 0.f};
      if (r < N) v = *(const float4*)(S + (size_t)r * lda + k0 + c);
      union { unsigned short us[4]; uint2 u2; } pk;
      pk.us[0] = f2bs(v.x); pk.us[1] = f2bs(v.y);
      pk.us[2] = f2bs(v.z); pk.us[3] = f2bs(v.w);
      *(uint2*)&sA[sr][c] = pk.u2;
    }
#pragma unroll
    for (int u = 0; u < 2; ++u) {   // B^T: 128x32 bf16
      int c = sc0b + u * 16;
      int nr = n_blk + sr;
      uint4 vb = {0, 0, 0, 0};
      if (nr < O) vb = *(const uint4*)(W2T + (size_t)nr * ldw + k0 + c);
      *(uint4*)&sB[sr][c] = vb;
    }
    __syncthreads();
    bf16x8 af[4];
#pragma unroll
    for (int im = 0; im < 4; ++im)
      af[im] = *(const bf16x8*)&sA[wm * 64 + im * 16 + lr][quad * 8];
#pragma unroll
    for (int jn = 0; jn < 4; ++jn) {
      bf16x8 bb = *(const bf16x8*)&sB[wn * 64 + jn * 16 + lr][quad * 8];
#pragma unroll
      for (int im = 0; im < 4; ++im)
        acc[im][jn] = __builtin_amdgcn_mfma_f32_16x16x32_bf16(af[im], bb, acc[im][jn], 0, 0, 0);
    }
    __syncthreads();
  }
#pragma unroll
  for (int jn = 0; jn < 4; ++jn) {
    int c = n_blk + wn * 64 + jn * 16 + lr;
    if (c >= O) continue;
    float b2v = b2[c];
#pragma unroll
    for (int im = 0; im < 4; ++im) {
      int mb = m_blk + wm * 64 + im * 16 + quad * 4;
#pragma unroll
      for (int rg = 0; rg < 4; ++rg) {
        int r = mb + rg;
        if (r >= N) continue;
        float rd = rdeg[r];
        float v = acc[im][jn][rg] * rd;
        size_t o = (size_t)r * O + c;
        if (first) {
          if (rd != 0.f) v += b2v;
          Eo[o] = v;
        } else {
          Eo[o] += v;
        }
      }
    }
  }
}

// ---------------- edge kernel: S[dst] += relu(C[dst] + B[src]) ----------------
__global__ __launch_bounds__(256) void k_edge(const int* __restrict__ ei, int E,
                                              const bf16* __restrict__ C,
                                              const bf16* __restrict__ B,
                                              float* __restrict__ S, int Hc) {
  int gw = (blockIdx.x * 256 + threadIdx.x) >> 6;
  int lane = threadIdx.x & 63;
  if (gw >= E) return;
  int src = ei[gw], dst = ei[E + gw];
  const uint32_t* Crow = reinterpret_cast<const uint32_t*>(C + (size_t)dst * Hc);
  const uint32_t* Brow = reinterpret_cast<const uint32_t*>(B + (size_t)src * Hc);
  float* Srow = S + (size_t)dst * Hc;
  for (int j2 = lane; j2 * 2 < Hc; j2 += 64) {
    uint32_t uc = Crow[j2], ub = Brow[j2];
    float v0 = __uint_as_float(uc << 16) + __uint_as_float(ub << 16);
    float v1 = __uint_as_float(uc & 0xffff0000u) + __uint_as_float(ub & 0xffff0000u);
    int j = j2 * 2;
    if (v0 > 0.f) unsafeAtomicAdd(&Srow[j], v0);
    if (v1 > 0.f) unsafeAtomicAdd(&Srow[j + 1], v1);
  }
}

// ---------------- BN stats ----------------
__global__ __launch_bounds__(256) void k_bn_stats(const float* __restrict__ Ef,
                                                  float* __restrict__ stats, int N, int O) {
  int r0 = blockIdx.x * 256;
  int rend = min(r0 + 256, N);
  for (int c = threadIdx.x; c < O; c += 256) {
    float s = 0.f, q = 0.f;
    for (int r = r0; r < rend; ++r) {
      float v = Ef[(size_t)r * O + c];
      s += v;
      q += v * v;
    }
    unsafeAtomicAdd(&stats[c], s);
    unsafeAtomicAdd(&stats[O + c], q);
  }
}

__global__ __launch_bounds__(256) void k_bn_finalize(const float* __restrict__ stats,
                                                     const float* __restrict__ gamma,
                                                     const float* __restrict__ beta,
                                                     float* __restrict__ scale,
                                                     float* __restrict__ shift, int N, int O) {
  int c = blockIdx.x * 256 + threadIdx.x;
  if (c >= O) return;
  float mu = stats[c] / (float)N;
  float var = stats[O + c] / (float)N - mu * mu;
  float sc = gamma[c] * rsqrtf(var + 1e-5f);
  scale[c] = sc;
  shift[c] = beta[c] - mu * sc;
}

// ---------------- BN-apply + relu + face scatter ----------------
__global__ __launch_bounds__(256) void k_scatter(const float* __restrict__ Ef,
                                                 const int* __restrict__ faces,
                                                 const float* __restrict__ scale,
                                                 const float* __restrict__ shift,
                                                 int use_bn, float* __restrict__ Vf,
                                                 int N, int O, int O3) {
  int idx = blockIdx.x * 256 + threadIdx.x;
  if (idx >= N * O) return;
  int n = idx / O;
  int c = idx - n * O;
  float v = Ef[idx];
  if (use_bn) v = fmaxf(fmaf(v, scale[c], shift[c]), 0.f);
  int g = c / O3;
  int vert = faces[n * 3 + g];
  unsafeAtomicAdd(&Vf[(size_t)vert * O3 + (c - g * O3)], v);
}

// ---------------- vertex mean gather back ----------------
__global__ __launch_bounds__(256) void k_gather_bf16(const float* __restrict__ Vf,
                                                     const int* __restrict__ faces,
                                                     const float* __restrict__ rv,
                                                     bf16* __restrict__ out,
                                                     int N, int O, int O3) {
  int idx = blockIdx.x * 256 + threadIdx.x;
  if (idx >= N * O) return;
  int n = idx / O;
  int c = idx - n * O;
  int g = c / O3;
  int vert = faces[n * 3 + g];
  out[idx] = f2bf(Vf[(size_t)vert * O3 + (c - g * O3)] * rv[vert]);
}

__global__ __launch_bounds__(256) void k_gather_f32(const float* __restrict__ Vf,
                                                    const int* __restrict__ faces,
                                                    const float* __restrict__ rv,
                                                    float* __restrict__ out,
                                                    int N, int O, int O3) {
  int idx = blockIdx.x * 256 + threadIdx.x;
  if (idx >= N * O) return;
  int n = idx / O;
  int c = idx - n * O;
  int g = c / O3;
  int vert = faces[n * 3 + g];
  out[idx] = Vf[(size_t)vert * O3 + (c - g * O3)] * rv[vert];
}

extern "C" void kernel_launch(void* const* d_in, const int* in_sizes, int n_in,
                              void* d_out, int out_size, void* d_ws, size_t ws_size,
                              hipStream_t stream) {
  (void)n_in; (void)out_size; (void)ws_size;
  const float* x = (const float*)d_in[0];
  const int* ei = (const int*)d_in[1];
  const int* faces = (const int*)d_in[2];
  const int N = in_sizes[0] / 16;
  const int E = in_sizes[1] / 2;
  const int V = 50000;

  char* p = (char*)d_ws;
  auto carve = [&](size_t bytes) -> char* {
    char* r = p;
    p += (bytes + 255) & ~(size_t)255;
    return r;
  };
  bf16* buf_h = (bf16*)carve((size_t)N * 384 * sizeof(bf16));
  float* buf_e = (float*)carve((size_t)N * 384 * sizeof(float));
  bf16* buf_C = (bf16*)carve((size_t)N * CHUNK * sizeof(bf16));
  bf16* buf_B = (bf16*)carve((size_t)N * CHUNK * sizeof(bf16));
  float* buf_S = (float*)carve((size_t)N * CHUNK * sizeof(float));
  float* buf_V = (float*)carve((size_t)V * 192 * sizeof(float));
  bf16* buf_WdT = (bf16*)carve((size_t)970000 * sizeof(bf16));
  bf16* buf_WbT = (bf16*)carve((size_t)970000 * sizeof(bf16));
  bf16* buf_W2T = (bf16*)carve((size_t)1350000 * sizeof(bf16));
  int* ideg = (int*)carve((size_t)N * 4);
  int* ivdeg = (int*)carve((size_t)V * 4);
  float* rdegN = (float*)carve((size_t)N * 4);
  float* rdegV = (float*)carve((size_t)V * 4);
  float* stats = (float*)carve(2 * 576 * 4);
  float* scale = (float*)carve(576 * 4);
  float* shift = (float*)carve(576 * 4);

  hipMemsetAsync(ideg, 0, (size_t)N * 4, stream);
  hipMemsetAsync(ivdeg, 0, (size_t)V * 4, stream);
  k_count<<<cdiv(E, 256), 256, 0, stream>>>(ei + E, ideg, E);
  k_count<<<cdiv(3 * N, 256), 256, 0, stream>>>(faces, ivdeg, 3 * N);
  k_recip<<<cdiv(N, 256), 256, 0, stream>>>(ideg, rdegN, N);
  k_recip<<<cdiv(V, 256), 256, 0, stream>>>(ivdeg, rdegV, V);

  k_embed<<<cdiv(N * 224, 256), 256, 0, stream>>>(x, buf_h, N);

  const int LF[5] = {196, 96, 192, 384, 384};
  const int LH[5] = {192, 384, 768, 768, 1152};
  const int LO[5] = {96, 192, 384, 384, 576};

  // per-layer offsets into transposed-weight buffers
  size_t off1 = 0, off2 = 0;

  for (int l = 0; l < 5; ++l) {
    const int F = LF[l], H = LH[l], O = LO[l], O3 = O / 3;
    const int F_pad = ((F + 31) / 32) * 32;
    const float* w1 = (const float*)d_in[4 + l * 4];
    const float* b1 = (const float*)d_in[5 + l * 4];
    const float* w2 = (const float*)d_in[6 + l * 4];
    const float* b2 = (const float*)d_in[7 + l * 4];
    float* Ebuf = (l == 4) ? (float*)d_out : buf_e;
    bf16* WdT = buf_WdT + off1;
    bf16* WbT = buf_WbT + off1;
    bf16* W2T = buf_W2T + off2;
    off1 += (size_t)H * F_pad;
    off2 += (size_t)O * H;

    k_prep_w1<<<cdiv(H * F_pad, 256), 256, 0, stream>>>(w1, WdT, WbT, F, H, F_pad);
    k_prep_w2<<<cdiv(O * H, 256), 256, 0, stream>>>(w2, W2T, H, O);

    for (int c0 = 0; c0 < H; c0 += CHUNK) {
      int Hc = (H - c0 < CHUNK) ? (H - c0) : CHUNK;
      dim3 g1(cdiv(N, 128), cdiv(Hc, 128));
      gemm1_mfma<<<g1, 256, 0, stream>>>(buf_h, F_pad,
                                         WdT + (size_t)c0 * F_pad, WbT + (size_t)c0 * F_pad,
                                         b1, c0, buf_C, buf_B, N, F_pad, Hc);
      hipMemsetAsync(buf_S, 0, (size_t)N * Hc * 4, stream);
      k_edge<<<cdiv(E * 64, 256), 256, 0, stream>>>(ei, E, buf_C, buf_B, buf_S, Hc);
      dim3 g2(cdiv(N, 128), cdiv(O, 128));
      gemm2_mfma<<<g2, 256, 0, stream>>>(buf_S, Hc, W2T + c0, H, b2, rdegN, Ebuf,
                                         N, Hc, O, c0 == 0 ? 1 : 0);
    }

    if (l < 4) {
      hipMemsetAsync(stats, 0, (size_t)2 * O * 4, stream);
      k_bn_stats<<<cdiv(N, 256), 256, 0, stream>>>(Ebuf, stats, N, O);
      k_bn_finalize<<<cdiv(O, 256), 256, 0, stream>>>(
          stats, (const float*)d_in[24 + l * 2], (const float*)d_in[25 + l * 2],
          scale, shift, N, O);
    }

    hipMemsetAsync(buf_V, 0, (size_t)V * O3 * 4, stream);
    k_scatter<<<cdiv(N * O, 256), 256, 0, stream>>>(Ebuf, faces, scale, shift,
                                                    (l < 4) ? 1 : 0, buf_V, N, O, O3);
    if (l < 4)
      k_gather_bf16<<<cdiv(N * O, 256), 256, 0, stream>>>(buf_V, faces, rdegV, buf_h, N, O, O3);
    else
      k_gather_f32<<<cdiv(N * O, 256), 256, 0, stream>>>(buf_V, faces, rdegV, (float*)d_out, N, O, O3);
  }
}